// Round 6
// baseline (320.429 us; speedup 1.0000x reference)
//
#include <hip/hip_runtime.h>
#include <hip/hip_bf16.h>
#include <hip/hip_cooperative_groups.h>
#include <math.h>

namespace cg = cooperative_groups;

// NT-Xent loss, N=4096, D=256 -> 2N=8192 rows.
// R17: R16's absmax (9.1875 == full ref loss vs zeroed out-buf) proves the
// cooperative launch FAILED SILENTLY (return code unchecked, nothing ran).
// Fix: occupancy-query the fused kernel, launch min(512, occ*256) blocks
// (kernel is gridDim.x-agnostic), CHECK the return code, and fall back to
// the verified R14 4-kernel path (90.8us, absmax 0) on any failure.
// Fused phases (grid.sync between, fences both sides):
//   A: prep units u = b, b+g,.. <512: normalize -> fp8 -> zT16 + pair sims.
//   B: simsum tiles t = b, b+g,.. <2080 (R13 LDS-staged fp8 Gram, 0 bank
//      conflicts).
//   C: logsum units u = b.. <128 -> logpart.
//   D: block 0: out = (sum logpart - 2*sum pairpart)/8192.

static constexpr int ROWS  = 8192;
static constexpr int NPAIR = 4096;
static constexpr int DIM   = 256;            // f32 elems per row / bytes per fp8 row
static constexpr int NTILE = 64 * 65 / 2;    // 2080
static constexpr float EXP_SCALE = 14.426950408889634f;  // 10/ln2

typedef float f32x4 __attribute__((ext_vector_type(4)));
typedef long  l2v  __attribute__((ext_vector_type(2)));

template <int CTRL>
__device__ __forceinline__ float dpp_add(float x) {
    int t = __builtin_amdgcn_update_dpp(
        0, __builtin_bit_cast(int, x), CTRL, 0xF, 0xF, true);
    return x + __builtin_bit_cast(float, t);
}
__device__ __forceinline__ float sum16(float x) {
    x = dpp_add<0xB1>(x);   // xor 1
    x = dpp_add<0x4E>(x);   // xor 2
    x = dpp_add<0x141>(x);  // xor 4 (row_half_mirror)
    x = dpp_add<0x140>(x);  // xor 8 (row_mirror)
    return x;
}
__device__ __forceinline__ float sum64(float x) {
    x = sum16(x);
    x += __shfl_xor(x, 16);
    x += __shfl_xor(x, 32);
    return x;
}

// ================= FUSED cooperative kernel =================
__global__ void __launch_bounds__(256, 2) fused_kernel(
        const float* __restrict__ z1, const float* __restrict__ z2,
        unsigned char* __restrict__ zT16, float* __restrict__ partial,
        float* __restrict__ pairpart, float* __restrict__ logpart,
        float* __restrict__ out) {
    cg::grid_group grid = cg::this_grid();

    __shared__ __align__(16) unsigned char lds[65536];

    const int tid  = threadIdx.x;
    const int wave = tid >> 6;
    const int lane = tid & 63;
    const int lc   = lane & 15;
    const int quad = lane >> 4;
    const int b    = blockIdx.x;
    const int g    = gridDim.x;

    // ---------- Phase A: prep ----------
    // Unit u handles pairs 8u..8u+7: z1 rows (slots 0..7), z2 rows (8..15).
    // Wave w owns slots {w,4+w,8+w,12+w}; it0/it2 = pair 8u+w, it1/it3 =
    // pair 8u+4+w.  zT16[(c2*8192+row)*16], c2 = quad*4+kk, 16B entry =
    //   z[row][64kk+8q..+7] ++ z[row][64kk+32+8q..+7]
    for (int u = b; u < NPAIR / 8; u += g) {
        __syncthreads();                  // Ls reuse guard across iterations
        int*   Ls = (int*)lds;            // 16 rows x 256B
        float* wp = (float*)(lds + 4096); // 4 floats
        const int p0 = u * 8;
        float4 v[4];
        float  invn[4];
        #pragma unroll
        for (int it = 0; it < 4; ++it) {
            const int s  = it * 4 + wave;          // slot 0..15
            const int pr = p0 + (s & 7);           // pair index
            const float* src = (s < 8) ? (z1 + (size_t)pr * DIM)
                                       : (z2 + (size_t)pr * DIM);
            v[it] = ((const float4*)src)[lane];
            float ss = sum64(v[it].x * v[it].x + v[it].y * v[it].y
                           + v[it].z * v[it].z + v[it].w * v[it].w);
            invn[it] = 1.0f / fmaxf(sqrtf(ss), 1e-12f);
            int p = __builtin_amdgcn_cvt_pk_fp8_f32(
                        v[it].x * invn[it], v[it].y * invn[it], 0, false);
            p     = __builtin_amdgcn_cvt_pk_fp8_f32(
                        v[it].z * invn[it], v[it].w * invn[it], p, true);
            Ls[s * 64 + lane] = p;
        }
        {
            float d0 = sum64(v[0].x * v[2].x + v[0].y * v[2].y
                           + v[0].z * v[2].z + v[0].w * v[2].w);
            float d1 = sum64(v[1].x * v[3].x + v[1].y * v[3].y
                           + v[1].z * v[3].z + v[1].w * v[3].w);
            if (lane == 0)
                wp[wave] = (d0 * invn[0] * invn[2]
                          + d1 * invn[1] * invn[3]) * 10.0f;
        }
        __syncthreads();
        const int c2 = tid >> 4;
        const int r  = tid & 15;
        const int grow = (r < 8) ? (p0 + r) : (NPAIR + p0 + (r - 8));
        const int q2  = c2 >> 2;
        const int kk  = c2 & 3;
        const int d0i = 16 * kk + 2 * q2;
        int4 o;
        o.x = Ls[r * 64 + d0i];
        o.y = Ls[r * 64 + d0i + 1];
        o.z = Ls[r * 64 + d0i + 8];
        o.w = Ls[r * 64 + d0i + 9];
        *(int4*)(zT16 + ((size_t)c2 * ROWS + grow) * 16) = o;
        if (tid == 0)
            pairpart[u] = wp[0] + wp[1] + wp[2] + wp[3];
    }
    __threadfence();
    grid.sync();
    __threadfence();

    // ---------- Phase B: simsum tiles ----------
    // LDS: A panel [0,32KB), B panel [32KB,64KB); 32 groups of 1KB, group
    // g2: kk=g2>>3, ig=g2&7. DMA dest = wave-uniform base + lane*16 ->
    // [q][row][16B]; compute reads whole 1KB groups -> 0 bank conflicts.
    const int waveRow = (wave >> 1) * 64;
    const int waveCol = (wave & 1) * 64;
    for (int t = b; t < NTILE; t += g) {
        int by = (int)floorf((129.0f - sqrtf(16641.0f - 8.0f * (float)t)) * 0.5f);
        by = max(0, min(by, 63));
        while (64 * (by + 1) - ((by + 1) * by) / 2 <= t) by++;
        while (64 * by - (by * (by - 1)) / 2 > t) by--;
        const int bx = by + (t - (64 * by - (by * (by - 1)) / 2));
        const int rowBase = by * 128;
        const int colBase = bx * 128;

        __syncthreads();   // LDS reuse guard
        {
            const int halfSel = wave >> 1;                   // 0=A, 1=B
            const int pbase   = halfSel ? colBase : rowBase;
            #pragma unroll
            for (int it = 0; it < 16; ++it) {
                const int g2 = ((wave & 1) << 4) | it;       // 0..31
                const int kk = g2 >> 3;
                const int ig = g2 & 7;
                const unsigned char* src = zT16
                    + ((size_t)(4 * quad + kk) * ROWS + pbase + 16 * ig + lc) * 16;
                __builtin_amdgcn_global_load_lds(
                    (const __attribute__((address_space(1))) unsigned int*)src,
                    (__attribute__((address_space(3))) unsigned int*)
                        &lds[(halfSel << 15) + kk * 8192 + ig * 1024],
                    16, 0, 0);
            }
        }
        __syncthreads();

        const int aig = (wave >> 1) * 4;
        const int bgi = (wave & 1) * 4;
        const unsigned char* lA = &lds[quad * 256 + lc * 16];
        const unsigned char* lB = &lds[32768 + quad * 256 + lc * 16];

        f32x4 acc[4][4];
        #pragma unroll
        for (int i = 0; i < 4; i++)
            #pragma unroll
            for (int j = 0; j < 4; j++)
                acc[i][j] = (f32x4)(0.0f);

        #pragma unroll
        for (int kk = 0; kk < 4; kk++) {
            l2v va[4], vb[4];
            #pragma unroll
            for (int i = 0; i < 4; i++)
                va[i] = *(const l2v*)(lA + kk * 8192 + (aig + i) * 1024);
            #pragma unroll
            for (int j = 0; j < 4; j++)
                vb[j] = *(const l2v*)(lB + kk * 8192 + (bgi + j) * 1024);
            #pragma unroll
            for (int i = 0; i < 4; i++)
                #pragma unroll
                for (int j = 0; j < 4; j++)
                    acc[i][j] = __builtin_amdgcn_mfma_f32_16x16x32_fp8_fp8(
                        va[i].x, vb[j].x, acc[i][j], 0, 0, 0);
            #pragma unroll
            for (int i = 0; i < 4; i++)
                #pragma unroll
                for (int j = 0; j < 4; j++)
                    acc[i][j] = __builtin_amdgcn_mfma_f32_16x16x32_fp8_fp8(
                        va[i].y, vb[j].y, acc[i][j], 0, 0, 0);
        }

        // Epilogue. C/D 16x16: col=lane&15, row=quad*4+reg [m89].
        // Unique-writer slots, SLOT-MAJOR: partial[slot*8192 + row].
        float* prow = partial + (size_t)(bx * 2 + (waveCol >> 6)) * ROWS;
        if (bx == by) {
            #pragma unroll
            for (int i = 0; i < 4; i++) {
                #pragma unroll
                for (int r = 0; r < 4; r++) {
                    const int grow = rowBase + waveRow + 16 * i + quad * 4 + r;
                    float s = 0.0f;
                    #pragma unroll
                    for (int j = 0; j < 4; j++) {
                        const int gcol = colBase + waveCol + 16 * j + lc;
                        float e = __builtin_amdgcn_exp2f(acc[i][j][r] * EXP_SCALE);
                        s += (grow == gcol) ? 0.0f : e;
                    }
                    s = sum16(s);
                    if (lc == 0) prow[grow] = s;
                }
            }
        } else {
            float* pcol = partial + (size_t)(by * 2 + (waveRow >> 6)) * ROWS;
            float colacc[4] = {0.0f, 0.0f, 0.0f, 0.0f};
            #pragma unroll
            for (int i = 0; i < 4; i++) {
                #pragma unroll
                for (int r = 0; r < 4; r++) {
                    const int grow = rowBase + waveRow + 16 * i + quad * 4 + r;
                    float s = 0.0f;
                    #pragma unroll
                    for (int j = 0; j < 4; j++) {
                        float e = __builtin_amdgcn_exp2f(acc[i][j][r] * EXP_SCALE);
                        s += e;
                        colacc[j] += e;
                    }
                    s = sum16(s);
                    if (lc == 0) prow[grow] = s;
                }
            }
            #pragma unroll
            for (int j = 0; j < 4; j++) {
                float c = colacc[j];
                c += __shfl_xor(c, 16);
                c += __shfl_xor(c, 32);
                if (lane < 16) pcol[colBase + waveCol + 16 * j + lc] = c;
            }
        }
    }
    __threadfence();
    grid.sync();
    __threadfence();

    // ---------- Phase C: logsum ----------
    for (int u = b; u < 128; u += g) {
        __syncthreads();
        float* red = (float*)lds;   // [4][64]
        const int r0 = u * 64;
        float s = 0.0f;
        #pragma unroll
        for (int k = 0; k < 32; ++k) {
            const int slot = wave + k * 4;
            s += partial[(size_t)slot * ROWS + r0 + lane];
        }
        red[wave * 64 + lane] = s;
        __syncthreads();
        if (wave == 0) {
            float rs = red[0 * 64 + lane] + red[1 * 64 + lane]
                     + red[2 * 64 + lane] + red[3 * 64 + lane];
            float lg = sum64(logf(rs));
            if (lane == 0) logpart[u] = lg;
        }
    }
    __threadfence();
    grid.sync();
    __threadfence();

    // ---------- Phase D: final (block 0) ----------
    if (b == 0) {
        float v = -2.0f * (pairpart[tid] + pairpart[tid + 256]);
        if (tid < 128) v += logpart[tid];
        v = sum64(v);
        float* wpart = (float*)lds;
        __syncthreads();
        if ((tid & 63) == 0) wpart[tid >> 6] = v;
        __syncthreads();
        if (tid == 0)
            out[0] = (wpart[0] + wpart[1] + wpart[2] + wpart[3])
                   * (1.0f / ROWS);
    }
}

// ================= FALLBACK: verified R14 4-kernel path =================
__global__ void __launch_bounds__(256) prep_kernel(
        const float* __restrict__ z1, const float* __restrict__ z2,
        unsigned char* __restrict__ zT16, float* __restrict__ pairpart) {
    __shared__ int Ls[16 * 64];
    __shared__ float wp[4];
    const int tid  = threadIdx.x;
    const int wave = tid >> 6;
    const int lane = tid & 63;
    const int p0   = blockIdx.x * 8;

    float4 v[4];
    float  invn[4];
    #pragma unroll
    for (int it = 0; it < 4; ++it) {
        const int s  = it * 4 + wave;
        const int pr = p0 + (s & 7);
        const float* src = (s < 8) ? (z1 + (size_t)pr * DIM)
                                   : (z2 + (size_t)pr * DIM);
        v[it] = ((const float4*)src)[lane];
        float ss = sum64(v[it].x * v[it].x + v[it].y * v[it].y
                       + v[it].z * v[it].z + v[it].w * v[it].w);
        invn[it] = 1.0f / fmaxf(sqrtf(ss), 1e-12f);
        int p = __builtin_amdgcn_cvt_pk_fp8_f32(
                    v[it].x * invn[it], v[it].y * invn[it], 0, false);
        p     = __builtin_amdgcn_cvt_pk_fp8_f32(
                    v[it].z * invn[it], v[it].w * invn[it], p, true);
        Ls[s * 64 + lane] = p;
    }
    {
        float d0 = sum64(v[0].x * v[2].x + v[0].y * v[2].y
                       + v[0].z * v[2].z + v[0].w * v[2].w);
        float d1 = sum64(v[1].x * v[3].x + v[1].y * v[3].y
                       + v[1].z * v[3].z + v[1].w * v[3].w);
        if (lane == 0)
            wp[wave] = (d0 * invn[0] * invn[2] + d1 * invn[1] * invn[3]) * 10.0f;
    }
    __syncthreads();
    const int c2 = tid >> 4;
    const int r  = tid & 15;
    const int grow = (r < 8) ? (p0 + r) : (NPAIR + p0 + (r - 8));
    const int quad = c2 >> 2;
    const int kk   = c2 & 3;
    const int d0i = 16 * kk + 2 * quad;
    int4 o;
    o.x = Ls[r * 64 + d0i];
    o.y = Ls[r * 64 + d0i + 1];
    o.z = Ls[r * 64 + d0i + 8];
    o.w = Ls[r * 64 + d0i + 9];
    *(int4*)(zT16 + ((size_t)c2 * ROWS + grow) * 16) = o;
    if (tid == 0)
        pairpart[blockIdx.x] = wp[0] + wp[1] + wp[2] + wp[3];
}

__global__ void __launch_bounds__(256, 2) simsum_kernel(
        const unsigned char* __restrict__ zT16, float* __restrict__ partial) {
    const int t = blockIdx.x;
    int by = (int)floorf((129.0f - sqrtf(16641.0f - 8.0f * (float)t)) * 0.5f);
    by = max(0, min(by, 63));
    while (64 * (by + 1) - ((by + 1) * by) / 2 <= t) by++;
    while (64 * by - (by * (by - 1)) / 2 > t) by--;
    const int bx = by + (t - (64 * by - (by * (by - 1)) / 2));
    const int rowBase = by * 128;
    const int colBase = bx * 128;

    const int tid  = threadIdx.x;
    const int wave = tid >> 6;
    const int lane = tid & 63;
    const int lc   = lane & 15;
    const int quad = lane >> 4;
    const int waveRow = (wave >> 1) * 64;
    const int waveCol = (wave & 1) * 64;

    __shared__ __align__(16) unsigned char lds[65536];

    {
        const int halfSel = wave >> 1;
        const int pbase   = halfSel ? colBase : rowBase;
        #pragma unroll
        for (int it = 0; it < 16; ++it) {
            const int g  = ((wave & 1) << 4) | it;
            const int kk = g >> 3;
            const int ig = g & 7;
            const unsigned char* src = zT16
                + ((size_t)(4 * quad + kk) * ROWS + pbase + 16 * ig + lc) * 16;
            __builtin_amdgcn_global_load_lds(
                (const __attribute__((address_space(1))) unsigned int*)src,
                (__attribute__((address_space(3))) unsigned int*)
                    &lds[(halfSel << 15) + kk * 8192 + ig * 1024],
                16, 0, 0);
        }
    }
    __syncthreads();

    const int aig = (wave >> 1) * 4;
    const int bgi = (wave & 1) * 4;
    const unsigned char* lA = &lds[quad * 256 + lc * 16];
    const unsigned char* lB = &lds[32768 + quad * 256 + lc * 16];

    f32x4 acc[4][4];
    #pragma unroll
    for (int i = 0; i < 4; i++)
        #pragma unroll
        for (int j = 0; j < 4; j++)
            acc[i][j] = (f32x4)(0.0f);

    #pragma unroll
    for (int kk = 0; kk < 4; kk++) {
        l2v va[4], vb[4];
        #pragma unroll
        for (int i = 0; i < 4; i++)
            va[i] = *(const l2v*)(lA + kk * 8192 + (aig + i) * 1024);
        #pragma unroll
        for (int j = 0; j < 4; j++)
            vb[j] = *(const l2v*)(lB + kk * 8192 + (bgi + j) * 1024);
        #pragma unroll
        for (int i = 0; i < 4; i++)
            #pragma unroll
            for (int j = 0; j < 4; j++)
                acc[i][j] = __builtin_amdgcn_mfma_f32_16x16x32_fp8_fp8(
                    va[i].x, vb[j].x, acc[i][j], 0, 0, 0);
        #pragma unroll
        for (int i = 0; i < 4; i++)
            #pragma unroll
            for (int j = 0; j < 4; j++)
                acc[i][j] = __builtin_amdgcn_mfma_f32_16x16x32_fp8_fp8(
                    va[i].y, vb[j].y, acc[i][j], 0, 0, 0);
    }

    float* prow = partial + (size_t)(bx * 2 + (waveCol >> 6)) * ROWS;
    if (bx == by) {
        #pragma unroll
        for (int i = 0; i < 4; i++) {
            #pragma unroll
            for (int r = 0; r < 4; r++) {
                const int grow = rowBase + waveRow + 16 * i + quad * 4 + r;
                float s = 0.0f;
                #pragma unroll
                for (int j = 0; j < 4; j++) {
                    const int gcol = colBase + waveCol + 16 * j + lc;
                    float e = __builtin_amdgcn_exp2f(acc[i][j][r] * EXP_SCALE);
                    s += (grow == gcol) ? 0.0f : e;
                }
                s = sum16(s);
                if (lc == 0) prow[grow] = s;
            }
        }
    } else {
        float* pcol = partial + (size_t)(by * 2 + (waveRow >> 6)) * ROWS;
        float colacc[4] = {0.0f, 0.0f, 0.0f, 0.0f};
        #pragma unroll
        for (int i = 0; i < 4; i++) {
            #pragma unroll
            for (int r = 0; r < 4; r++) {
                const int grow = rowBase + waveRow + 16 * i + quad * 4 + r;
                float s = 0.0f;
                #pragma unroll
                for (int j = 0; j < 4; j++) {
                    float e = __builtin_amdgcn_exp2f(acc[i][j][r] * EXP_SCALE);
                    s += e;
                    colacc[j] += e;
                }
                s = sum16(s);
                if (lc == 0) prow[grow] = s;
            }
        }
        #pragma unroll
        for (int j = 0; j < 4; j++) {
            float c = colacc[j];
            c += __shfl_xor(c, 16);
            c += __shfl_xor(c, 32);
            if (lane < 16) pcol[colBase + waveCol + 16 * j + lc] = c;
        }
    }
}

__global__ void __launch_bounds__(256) logsum_kernel(
        const float* __restrict__ partial, float* __restrict__ logpart) {
    const int tid  = threadIdx.x;
    const int wave = tid >> 6;
    const int lane = tid & 63;
    const int r0 = blockIdx.x * 64;
    float s = 0.0f;
    #pragma unroll
    for (int k = 0; k < 32; ++k) {
        const int slot = wave + k * 4;
        s += partial[(size_t)slot * ROWS + r0 + lane];
    }
    __shared__ float red[4][64];
    red[wave][lane] = s;
    __syncthreads();
    if (wave == 0) {
        float rs = red[0][lane] + red[1][lane] + red[2][lane] + red[3][lane];
        float lg = sum64(logf(rs));
        if (lane == 0) logpart[blockIdx.x] = lg;
    }
}

__global__ void __launch_bounds__(256) final_kernel(
        const float* __restrict__ logpart, const float* __restrict__ pairpart,
        float* __restrict__ out) {
    const int tid = threadIdx.x;
    float s = -2.0f * (pairpart[tid] + pairpart[tid + 256]);
    if (tid < 128) s += logpart[tid];
    s = sum64(s);
    __shared__ float wpart[4];
    if ((tid & 63) == 0) wpart[tid >> 6] = s;
    __syncthreads();
    if (tid == 0)
        out[0] = (wpart[0] + wpart[1] + wpart[2] + wpart[3]) * (1.0f / ROWS);
}

extern "C" void kernel_launch(void* const* d_in, const int* in_sizes, int n_in,
                              void* d_out, int out_size, void* d_ws, size_t ws_size,
                              hipStream_t stream) {
    const float* z1 = (const float*)d_in[0];
    const float* z2 = (const float*)d_in[1];
    float* out = (float*)d_out;

    char* ws = (char*)d_ws;
    unsigned char* zT16 = (unsigned char*)ws;                        // 2 MiB
    float* partial  = (float*)(ws + (size_t)2 * 1024 * 1024);        // 4 MiB [slot][row]
    float* pairpart = (float*)(ws + (size_t)6 * 1024 * 1024);        // 2 KiB (512)
    float* logpart  = (float*)(ws + (size_t)6 * 1024 * 1024 + 4096); // 512 B (128)

    // Max co-resident blocks for the fused kernel (cached).
    static int coop_per_cu = -1;
    if (coop_per_cu < 0) {
        int n = 0;
        if (hipOccupancyMaxActiveBlocksPerMultiprocessor(
                &n, fused_kernel, 256, (size_t)0) != hipSuccess)
            n = 0;
        coop_per_cu = n;
    }

    bool launched = false;
    if (coop_per_cu >= 1) {
        int maxGrid = coop_per_cu * 256;          // 256 CUs on MI355X
        int g = maxGrid < 512 ? maxGrid : 512;
        if (g >= 128) {
            void* args[] = { (void*)&z1, (void*)&z2, (void*)&zT16,
                             (void*)&partial, (void*)&pairpart,
                             (void*)&logpart, (void*)&out };
            if (hipLaunchCooperativeKernel((const void*)fused_kernel,
                                           dim3(g), dim3(256), args, 0,
                                           stream) == hipSuccess)
                launched = true;
        }
    }

    if (!launched) {   // verified R14 path
        prep_kernel<<<NPAIR / 8, 256, 0, stream>>>(z1, z2, zT16, pairpart);
        simsum_kernel<<<NTILE, 256, 0, stream>>>(zT16, partial);
        logsum_kernel<<<ROWS / 64, 256, 0, stream>>>(partial, logpart);
        final_kernel<<<1, 256, 0, stream>>>(logpart, pairpart, out);
    }
}

// Round 7
// 242.103 us; speedup vs baseline: 1.3235x; 1.3235x over previous
//
#include <hip/hip_runtime.h>
#include <hip/hip_bf16.h>
#include <math.h>

// NT-Xent loss, N=4096, D=256 -> 2N=8192 rows.
// R18: R16 proved grid.sync() costs ~90us each on this config (fused ran
// correct but 414us, MfmaUtil 1.7% = pure stall) -> coop fusion dead.
// Replacement: last-block-done counter (no spin, no grid barrier).
//   K1 prep: normalize -> fp8 -> zT16 + pair sims; zero rowsum + counter.
//   K2 simsum: R13 LDS-staged fp8 Gram (verified, 0 bank conflicts);
//      epilogue atomicAdds row/col exp-sums DIRECTLY into rowsum[8192]
//      (partial buffer + logsum dispatch eliminated, -8MB traffic);
//      unique last block (fetch_add == NTILE-1) computes
//      out = (sum log(rowsum) - 2*sum pairpart)/8192.
// 2 dispatches (was 4). Float-atomic ordering noise ~1e-5 << 0.18 threshold.

static constexpr int ROWS  = 8192;
static constexpr int NPAIR = 4096;
static constexpr int DIM   = 256;            // f32 elems per row / bytes per fp8 row
static constexpr int NTILE = 64 * 65 / 2;    // 2080
static constexpr float EXP_SCALE = 14.426950408889634f;  // 10/ln2

typedef float f32x4 __attribute__((ext_vector_type(4)));
typedef long  l2v  __attribute__((ext_vector_type(2)));

template <int CTRL>
__device__ __forceinline__ float dpp_add(float x) {
    int t = __builtin_amdgcn_update_dpp(
        0, __builtin_bit_cast(int, x), CTRL, 0xF, 0xF, true);
    return x + __builtin_bit_cast(float, t);
}
__device__ __forceinline__ float sum16(float x) {
    x = dpp_add<0xB1>(x);   // xor 1
    x = dpp_add<0x4E>(x);   // xor 2
    x = dpp_add<0x141>(x);  // xor 4 (row_half_mirror)
    x = dpp_add<0x140>(x);  // xor 8 (row_mirror)
    return x;
}
__device__ __forceinline__ float sum64(float x) {
    x = sum16(x);
    x += __shfl_xor(x, 16);
    x += __shfl_xor(x, 32);
    return x;
}

// ---------------- K1: normalize -> fp8 -> zT16, + pair sims ----------------
// Block b handles pairs p0..p0+7 (p0 = 8b): z1 rows (slots 0..7), z2 rows
// (slots 8..15). Wave w owns slots {w,4+w,8+w,12+w}; it0/it2 = pair p0+w,
// it1/it3 = pair p0+4+w.
// zT16[(c2*8192+row)*16] : c2 = quad*4+kk, entry = 16B =
//   z[row][64kk+8q..+7] ++ z[row][64kk+32+8q..+7]
// Also zeroes rowsum (16 floats/block) and counter (d_ws is re-poisoned).
__global__ void __launch_bounds__(256) prep_kernel(
        const float* __restrict__ z1, const float* __restrict__ z2,
        unsigned char* __restrict__ zT16, float* __restrict__ pairpart,
        float* __restrict__ rowsum, unsigned int* __restrict__ counter) {
    __shared__ int Ls[16 * 64];   // 16 rows x 256B (fp8)
    __shared__ float wp[4];
    const int tid  = threadIdx.x;
    const int wave = tid >> 6;
    const int lane = tid & 63;
    const int p0   = blockIdx.x * 8;

    if (tid < 16) rowsum[blockIdx.x * 16 + tid] = 0.0f;
    if (blockIdx.x == 0 && tid == 16) counter[0] = 0u;

    float4 v[4];
    float  invn[4];
    #pragma unroll
    for (int it = 0; it < 4; ++it) {
        const int s  = it * 4 + wave;          // slot 0..15
        const int pr = p0 + (s & 7);           // pair index
        const float* src = (s < 8) ? (z1 + (size_t)pr * DIM)
                                   : (z2 + (size_t)pr * DIM);
        v[it] = ((const float4*)src)[lane];
        float ss = sum64(v[it].x * v[it].x + v[it].y * v[it].y
                       + v[it].z * v[it].z + v[it].w * v[it].w);
        invn[it] = 1.0f / fmaxf(sqrtf(ss), 1e-12f);
        int p = __builtin_amdgcn_cvt_pk_fp8_f32(
                    v[it].x * invn[it], v[it].y * invn[it], 0, false);
        p     = __builtin_amdgcn_cvt_pk_fp8_f32(
                    v[it].z * invn[it], v[it].w * invn[it], p, true);
        Ls[s * 64 + lane] = p;
    }
    // pair sims: (it0,it2) = pair p0+wave, (it1,it3) = pair p0+4+wave
    {
        float d0 = sum64(v[0].x * v[2].x + v[0].y * v[2].y
                       + v[0].z * v[2].z + v[0].w * v[2].w);
        float d1 = sum64(v[1].x * v[3].x + v[1].y * v[3].y
                       + v[1].z * v[3].z + v[1].w * v[3].w);
        if (lane == 0)
            wp[wave] = (d0 * invn[0] * invn[2] + d1 * invn[1] * invn[3]) * 10.0f;
    }
    __syncthreads();
    // thread t -> c2 = t>>4, row-slot r = t&15
    const int c2 = tid >> 4;
    const int r  = tid & 15;
    const int grow = (r < 8) ? (p0 + r) : (NPAIR + p0 + (r - 8));
    const int quad = c2 >> 2;
    const int kk   = c2 & 3;
    const int d0i = 16 * kk + 2 * quad;
    int4 o;
    o.x = Ls[r * 64 + d0i];
    o.y = Ls[r * 64 + d0i + 1];
    o.z = Ls[r * 64 + d0i + 8];
    o.w = Ls[r * 64 + d0i + 9];
    *(int4*)(zT16 + ((size_t)c2 * ROWS + grow) * 16) = o;
    if (tid == 0)
        pairpart[blockIdx.x] = wp[0] + wp[1] + wp[2] + wp[3];
}

// ---------------- K2: symmetric fp8 Gram + atomic rowsum + tail ----------
// LDS: A panel [0,32KB), B panel [32KB,64KB); 32 groups of 1KB, group g:
// kk=g>>3, ig=g&7. DMA dest = wave-uniform base + lane*16 -> [q][row][16B];
// compute reads whole 1KB groups contiguously -> 0 bank conflicts.
__global__ void __launch_bounds__(256, 2) simsum_kernel(
        const unsigned char* __restrict__ zT16, float* __restrict__ rowsum,
        const float* __restrict__ pairpart, unsigned int* __restrict__ counter,
        float* __restrict__ out) {
    // decode linear tile index -> (by, bx), bx >= by
    const int t = blockIdx.x;
    int by = (int)floorf((129.0f - sqrtf(16641.0f - 8.0f * (float)t)) * 0.5f);
    by = max(0, min(by, 63));
    while (64 * (by + 1) - ((by + 1) * by) / 2 <= t) by++;
    while (64 * by - (by * (by - 1)) / 2 > t) by--;
    const int bx = by + (t - (64 * by - (by * (by - 1)) / 2));
    const int rowBase = by * 128;
    const int colBase = bx * 128;

    const int tid  = threadIdx.x;
    const int wave = tid >> 6;
    const int lane = tid & 63;
    const int lc   = lane & 15;
    const int quad = lane >> 4;
    const int waveRow = (wave >> 1) * 64;
    const int waveCol = (wave & 1) * 64;

    __shared__ __align__(16) unsigned char lds[65536];

    // ---- stage both panels: waves 0,1 -> A rows, waves 2,3 -> B cols ----
    {
        const int halfSel = wave >> 1;                   // 0=A, 1=B
        const int pbase   = halfSel ? colBase : rowBase;
        #pragma unroll
        for (int it = 0; it < 16; ++it) {
            const int g  = ((wave & 1) << 4) | it;       // 0..31
            const int kk = g >> 3;
            const int ig = g & 7;
            const unsigned char* src = zT16
                + ((size_t)(4 * quad + kk) * ROWS + pbase + 16 * ig + lc) * 16;
            __builtin_amdgcn_global_load_lds(
                (const __attribute__((address_space(1))) unsigned int*)src,
                (__attribute__((address_space(3))) unsigned int*)
                    &lds[(halfSel << 15) + kk * 8192 + ig * 1024],
                16, 0, 0);
        }
    }
    __syncthreads();

    // ---- compute: pure ds_read_b128 + MFMA ----
    const int aig = (wave >> 1) * 4;
    const int bgi = (wave & 1) * 4;
    const unsigned char* lA = &lds[quad * 256 + lc * 16];
    const unsigned char* lB = &lds[32768 + quad * 256 + lc * 16];

    f32x4 acc[4][4];
    #pragma unroll
    for (int i = 0; i < 4; i++)
        #pragma unroll
        for (int j = 0; j < 4; j++)
            acc[i][j] = (f32x4)(0.0f);

    #pragma unroll
    for (int kk = 0; kk < 4; kk++) {
        l2v va[4], vb[4];
        #pragma unroll
        for (int i = 0; i < 4; i++)
            va[i] = *(const l2v*)(lA + kk * 8192 + (aig + i) * 1024);
        #pragma unroll
        for (int j = 0; j < 4; j++)
            vb[j] = *(const l2v*)(lB + kk * 8192 + (bgi + j) * 1024);
        #pragma unroll
        for (int i = 0; i < 4; i++)
            #pragma unroll
            for (int j = 0; j < 4; j++)
                acc[i][j] = __builtin_amdgcn_mfma_f32_16x16x32_fp8_fp8(
                    va[i].x, vb[j].x, acc[i][j], 0, 0, 0);
        #pragma unroll
        for (int i = 0; i < 4; i++)
            #pragma unroll
            for (int j = 0; j < 4; j++)
                acc[i][j] = __builtin_amdgcn_mfma_f32_16x16x32_fp8_fp8(
                    va[i].y, vb[j].y, acc[i][j], 0, 0, 0);
    }

    // Epilogue. C/D 16x16: col=lane&15, row=quad*4+reg [m89].
    // Row/col exp-sums -> atomicAdd straight into rowsum[8192].
    if (bx == by) {
        #pragma unroll
        for (int i = 0; i < 4; i++) {
            #pragma unroll
            for (int r = 0; r < 4; r++) {
                const int grow = rowBase + waveRow + 16 * i + quad * 4 + r;
                float s = 0.0f;
                #pragma unroll
                for (int j = 0; j < 4; j++) {
                    const int gcol = colBase + waveCol + 16 * j + lc;
                    float e = __builtin_amdgcn_exp2f(acc[i][j][r] * EXP_SCALE);
                    s += (grow == gcol) ? 0.0f : e;
                }
                s = sum16(s);
                if (lc == 0) atomicAdd(&rowsum[grow], s);
            }
        }
    } else {
        float colacc[4] = {0.0f, 0.0f, 0.0f, 0.0f};
        #pragma unroll
        for (int i = 0; i < 4; i++) {
            #pragma unroll
            for (int r = 0; r < 4; r++) {
                const int grow = rowBase + waveRow + 16 * i + quad * 4 + r;
                float s = 0.0f;
                #pragma unroll
                for (int j = 0; j < 4; j++) {
                    float e = __builtin_amdgcn_exp2f(acc[i][j][r] * EXP_SCALE);
                    s += e;
                    colacc[j] += e;
                }
                s = sum16(s);
                if (lc == 0) atomicAdd(&rowsum[grow], s);
            }
        }
        #pragma unroll
        for (int j = 0; j < 4; j++) {
            float c = colacc[j];
            c += __shfl_xor(c, 16);
            c += __shfl_xor(c, 32);
            if (lane < 16)
                atomicAdd(&rowsum[colBase + waveCol + 16 * j + lc], c);
        }
    }

    // ---- last-block-done tail ----
    __threadfence();          // order this thread's atomics before counter
    __syncthreads();          // all waves of this block done
    __shared__ unsigned int sdone;
    if (tid == 0)
        sdone = __hip_atomic_fetch_add(counter, 1u, __ATOMIC_ACQ_REL,
                                       __HIP_MEMORY_SCOPE_AGENT);
    __syncthreads();
    if (sdone == NTILE - 1) {     // unique winner: all rowsum adds visible
        __threadfence();
        float v = -2.0f * (pairpart[tid] + pairpart[tid + 256]);
        #pragma unroll
        for (int k = 0; k < 32; ++k) {
            float rs = __hip_atomic_load(&rowsum[tid + 256 * k],
                                         __ATOMIC_RELAXED,
                                         __HIP_MEMORY_SCOPE_AGENT);
            v += logf(rs);
        }
        v = sum64(v);
        float* wpart = (float*)lds;
        __syncthreads();
        if ((tid & 63) == 0) wpart[tid >> 6] = v;
        __syncthreads();
        if (tid == 0)
            out[0] = (wpart[0] + wpart[1] + wpart[2] + wpart[3])
                   * (1.0f / ROWS);
    }
}

extern "C" void kernel_launch(void* const* d_in, const int* in_sizes, int n_in,
                              void* d_out, int out_size, void* d_ws, size_t ws_size,
                              hipStream_t stream) {
    const float* z1 = (const float*)d_in[0];
    const float* z2 = (const float*)d_in[1];
    float* out = (float*)d_out;

    char* ws = (char*)d_ws;
    unsigned char* zT16 = (unsigned char*)ws;                         // 2 MiB
    float* rowsum   = (float*)(ws + (size_t)2 * 1024 * 1024);         // 32 KiB
    float* pairpart = (float*)(ws + (size_t)2 * 1024 * 1024 + 32768); // 2 KiB
    unsigned int* counter =
        (unsigned int*)(ws + (size_t)2 * 1024 * 1024 + 36864);        // 4 B

    prep_kernel<<<NPAIR / 8, 256, 0, stream>>>(
        z1, z2, zT16, pairpart, rowsum, counter);
    simsum_kernel<<<NTILE, 256, 0, stream>>>(
        zT16, rowsum, pairpart, counter, out);
}

// Round 8
// 108.587 us; speedup vs baseline: 2.9509x; 2.2296x over previous
//
#include <hip/hip_runtime.h>
#include <hip/hip_bf16.h>
#include <math.h>

// NT-Xent loss, N=4096, D=256 -> 2N=8192 rows.
// R19: R18's counters nailed it: simsum=184us, MfmaUtil 3.7%, 19MB@104GB/s
// = serialization. Cause: per-block __threadfence() (device release ->
// buffer_wbl2 = full L2 writeback) + ACQ_REL fetch_add (wbl2+inv) x2080
// blocks. Fix: rowsum atomics are device-scope HW atomics at the common
// coherence point (never dirty local L2); __syncthreads() drains vmcnt(0)
// so they are PERFORMED before the counter bump issues -> plain atomicAdd
// counter, no fences. Only the single winning tail block does one acquire
// __threadfence() before reading rowsum. Datapath identical to R18 (passed,
// absmax 0.0) -- only redundant cache-maintenance deleted.
//   K1 prep: normalize -> fp8 -> zT16 + pair sims; zero rowsum + counter.
//   K2 simsum: LDS-staged fp8 Gram (0 bank conflicts) + atomic rowsum +
//      last-block tail: out = (sum log(rowsum) - 2*sum pairpart)/8192.
// 2 dispatches.

static constexpr int ROWS  = 8192;
static constexpr int NPAIR = 4096;
static constexpr int DIM   = 256;            // f32 elems per row / bytes per fp8 row
static constexpr int NTILE = 64 * 65 / 2;    // 2080
static constexpr float EXP_SCALE = 14.426950408889634f;  // 10/ln2

typedef float f32x4 __attribute__((ext_vector_type(4)));
typedef long  l2v  __attribute__((ext_vector_type(2)));

template <int CTRL>
__device__ __forceinline__ float dpp_add(float x) {
    int t = __builtin_amdgcn_update_dpp(
        0, __builtin_bit_cast(int, x), CTRL, 0xF, 0xF, true);
    return x + __builtin_bit_cast(float, t);
}
__device__ __forceinline__ float sum16(float x) {
    x = dpp_add<0xB1>(x);   // xor 1
    x = dpp_add<0x4E>(x);   // xor 2
    x = dpp_add<0x141>(x);  // xor 4 (row_half_mirror)
    x = dpp_add<0x140>(x);  // xor 8 (row_mirror)
    return x;
}
__device__ __forceinline__ float sum64(float x) {
    x = sum16(x);
    x += __shfl_xor(x, 16);
    x += __shfl_xor(x, 32);
    return x;
}

// ---------------- K1: normalize -> fp8 -> zT16, + pair sims ----------------
// Block b handles pairs p0..p0+7 (p0 = 8b): z1 rows (slots 0..7), z2 rows
// (slots 8..15). Wave w owns slots {w,4+w,8+w,12+w}; it0/it2 = pair p0+w,
// it1/it3 = pair p0+4+w.
// zT16[(c2*8192+row)*16] : c2 = quad*4+kk, entry = 16B =
//   z[row][64kk+8q..+7] ++ z[row][64kk+32+8q..+7]
// Also zeroes rowsum (16 floats/block) and counter (d_ws is re-poisoned).
__global__ void __launch_bounds__(256) prep_kernel(
        const float* __restrict__ z1, const float* __restrict__ z2,
        unsigned char* __restrict__ zT16, float* __restrict__ pairpart,
        float* __restrict__ rowsum, unsigned int* __restrict__ counter) {
    __shared__ int Ls[16 * 64];   // 16 rows x 256B (fp8)
    __shared__ float wp[4];
    const int tid  = threadIdx.x;
    const int wave = tid >> 6;
    const int lane = tid & 63;
    const int p0   = blockIdx.x * 8;

    if (tid < 16) rowsum[blockIdx.x * 16 + tid] = 0.0f;
    if (blockIdx.x == 0 && tid == 16) counter[0] = 0u;

    float4 v[4];
    float  invn[4];
    #pragma unroll
    for (int it = 0; it < 4; ++it) {
        const int s  = it * 4 + wave;          // slot 0..15
        const int pr = p0 + (s & 7);           // pair index
        const float* src = (s < 8) ? (z1 + (size_t)pr * DIM)
                                   : (z2 + (size_t)pr * DIM);
        v[it] = ((const float4*)src)[lane];
        float ss = sum64(v[it].x * v[it].x + v[it].y * v[it].y
                       + v[it].z * v[it].z + v[it].w * v[it].w);
        invn[it] = 1.0f / fmaxf(sqrtf(ss), 1e-12f);
        int p = __builtin_amdgcn_cvt_pk_fp8_f32(
                    v[it].x * invn[it], v[it].y * invn[it], 0, false);
        p     = __builtin_amdgcn_cvt_pk_fp8_f32(
                    v[it].z * invn[it], v[it].w * invn[it], p, true);
        Ls[s * 64 + lane] = p;
    }
    // pair sims: (it0,it2) = pair p0+wave, (it1,it3) = pair p0+4+wave
    {
        float d0 = sum64(v[0].x * v[2].x + v[0].y * v[2].y
                       + v[0].z * v[2].z + v[0].w * v[2].w);
        float d1 = sum64(v[1].x * v[3].x + v[1].y * v[3].y
                       + v[1].z * v[3].z + v[1].w * v[3].w);
        if (lane == 0)
            wp[wave] = (d0 * invn[0] * invn[2] + d1 * invn[1] * invn[3]) * 10.0f;
    }
    __syncthreads();
    // thread t -> c2 = t>>4, row-slot r = t&15
    const int c2 = tid >> 4;
    const int r  = tid & 15;
    const int grow = (r < 8) ? (p0 + r) : (NPAIR + p0 + (r - 8));
    const int quad = c2 >> 2;
    const int kk   = c2 & 3;
    const int d0i = 16 * kk + 2 * quad;
    int4 o;
    o.x = Ls[r * 64 + d0i];
    o.y = Ls[r * 64 + d0i + 1];
    o.z = Ls[r * 64 + d0i + 8];
    o.w = Ls[r * 64 + d0i + 9];
    *(int4*)(zT16 + ((size_t)c2 * ROWS + grow) * 16) = o;
    if (tid == 0)
        pairpart[blockIdx.x] = wp[0] + wp[1] + wp[2] + wp[3];
}

// ---------------- K2: symmetric fp8 Gram + atomic rowsum + tail ----------
// LDS: A panel [0,32KB), B panel [32KB,64KB); 32 groups of 1KB, group g:
// kk=g>>3, ig=g&7. DMA dest = wave-uniform base + lane*16 -> [q][row][16B];
// compute reads whole 1KB groups contiguously -> 0 bank conflicts.
__global__ void __launch_bounds__(256, 2) simsum_kernel(
        const unsigned char* __restrict__ zT16, float* __restrict__ rowsum,
        const float* __restrict__ pairpart, unsigned int* __restrict__ counter,
        float* __restrict__ out) {
    // decode linear tile index -> (by, bx), bx >= by
    const int t = blockIdx.x;
    int by = (int)floorf((129.0f - sqrtf(16641.0f - 8.0f * (float)t)) * 0.5f);
    by = max(0, min(by, 63));
    while (64 * (by + 1) - ((by + 1) * by) / 2 <= t) by++;
    while (64 * by - (by * (by - 1)) / 2 > t) by--;
    const int bx = by + (t - (64 * by - (by * (by - 1)) / 2));
    const int rowBase = by * 128;
    const int colBase = bx * 128;

    const int tid  = threadIdx.x;
    const int wave = tid >> 6;
    const int lane = tid & 63;
    const int lc   = lane & 15;
    const int quad = lane >> 4;
    const int waveRow = (wave >> 1) * 64;
    const int waveCol = (wave & 1) * 64;

    __shared__ __align__(16) unsigned char lds[65536];

    // ---- stage both panels: waves 0,1 -> A rows, waves 2,3 -> B cols ----
    {
        const int halfSel = wave >> 1;                   // 0=A, 1=B
        const int pbase   = halfSel ? colBase : rowBase;
        #pragma unroll
        for (int it = 0; it < 16; ++it) {
            const int g  = ((wave & 1) << 4) | it;       // 0..31
            const int kk = g >> 3;
            const int ig = g & 7;
            const unsigned char* src = zT16
                + ((size_t)(4 * quad + kk) * ROWS + pbase + 16 * ig + lc) * 16;
            __builtin_amdgcn_global_load_lds(
                (const __attribute__((address_space(1))) unsigned int*)src,
                (__attribute__((address_space(3))) unsigned int*)
                    &lds[(halfSel << 15) + kk * 8192 + ig * 1024],
                16, 0, 0);
        }
    }
    __syncthreads();

    // ---- compute: pure ds_read_b128 + MFMA ----
    const int aig = (wave >> 1) * 4;
    const int bgi = (wave & 1) * 4;
    const unsigned char* lA = &lds[quad * 256 + lc * 16];
    const unsigned char* lB = &lds[32768 + quad * 256 + lc * 16];

    f32x4 acc[4][4];
    #pragma unroll
    for (int i = 0; i < 4; i++)
        #pragma unroll
        for (int j = 0; j < 4; j++)
            acc[i][j] = (f32x4)(0.0f);

    #pragma unroll
    for (int kk = 0; kk < 4; kk++) {
        l2v va[4], vb[4];
        #pragma unroll
        for (int i = 0; i < 4; i++)
            va[i] = *(const l2v*)(lA + kk * 8192 + (aig + i) * 1024);
        #pragma unroll
        for (int j = 0; j < 4; j++)
            vb[j] = *(const l2v*)(lB + kk * 8192 + (bgi + j) * 1024);
        #pragma unroll
        for (int i = 0; i < 4; i++)
            #pragma unroll
            for (int j = 0; j < 4; j++)
                acc[i][j] = __builtin_amdgcn_mfma_f32_16x16x32_fp8_fp8(
                    va[i].x, vb[j].x, acc[i][j], 0, 0, 0);
        #pragma unroll
        for (int i = 0; i < 4; i++)
            #pragma unroll
            for (int j = 0; j < 4; j++)
                acc[i][j] = __builtin_amdgcn_mfma_f32_16x16x32_fp8_fp8(
                    va[i].y, vb[j].y, acc[i][j], 0, 0, 0);
    }

    // Epilogue. C/D 16x16: col=lane&15, row=quad*4+reg [m89].
    // Row/col exp-sums -> device-scope atomicAdd into rowsum[8192].
    if (bx == by) {
        #pragma unroll
        for (int i = 0; i < 4; i++) {
            #pragma unroll
            for (int r = 0; r < 4; r++) {
                const int grow = rowBase + waveRow + 16 * i + quad * 4 + r;
                float s = 0.0f;
                #pragma unroll
                for (int j = 0; j < 4; j++) {
                    const int gcol = colBase + waveCol + 16 * j + lc;
                    float e = __builtin_amdgcn_exp2f(acc[i][j][r] * EXP_SCALE);
                    s += (grow == gcol) ? 0.0f : e;
                }
                s = sum16(s);
                if (lc == 0) atomicAdd(&rowsum[grow], s);
            }
        }
    } else {
        float colacc[4] = {0.0f, 0.0f, 0.0f, 0.0f};
        #pragma unroll
        for (int i = 0; i < 4; i++) {
            #pragma unroll
            for (int r = 0; r < 4; r++) {
                const int grow = rowBase + waveRow + 16 * i + quad * 4 + r;
                float s = 0.0f;
                #pragma unroll
                for (int j = 0; j < 4; j++) {
                    float e = __builtin_amdgcn_exp2f(acc[i][j][r] * EXP_SCALE);
                    s += e;
                    colacc[j] += e;
                }
                s = sum16(s);
                if (lc == 0) atomicAdd(&rowsum[grow], s);
            }
        }
        #pragma unroll
        for (int j = 0; j < 4; j++) {
            float c = colacc[j];
            c += __shfl_xor(c, 16);
            c += __shfl_xor(c, 32);
            if (lane < 16)
                atomicAdd(&rowsum[colBase + waveCol + 16 * j + lc], c);
        }
    }

    // ---- last-block-done tail (NO per-block fences: the rowsum atomics
    // are device-scope RMWs at the common coherence point; __syncthreads'
    // vmcnt(0) drain means they are PERFORMED before the counter bump) ----
    __syncthreads();
    __shared__ unsigned int sdone;
    if (tid == 0)
        sdone = atomicAdd(counter, 1u);     // device-scope, no cache ops
    __syncthreads();
    if (sdone == NTILE - 1) {     // unique winner: all rowsum adds visible
        __threadfence();          // ONE block: invalidate local caches
        float v = -2.0f * (pairpart[tid] + pairpart[tid + 256]);
        #pragma unroll
        for (int k = 0; k < 32; ++k) {
            float rs = __hip_atomic_load(&rowsum[tid + 256 * k],
                                         __ATOMIC_RELAXED,
                                         __HIP_MEMORY_SCOPE_AGENT);
            v += logf(rs);
        }
        v = sum64(v);
        float* wpart = (float*)lds;
        __syncthreads();
        if ((tid & 63) == 0) wpart[tid >> 6] = v;
        __syncthreads();
        if (tid == 0)
            out[0] = (wpart[0] + wpart[1] + wpart[2] + wpart[3])
                   * (1.0f / ROWS);
    }
}

extern "C" void kernel_launch(void* const* d_in, const int* in_sizes, int n_in,
                              void* d_out, int out_size, void* d_ws, size_t ws_size,
                              hipStream_t stream) {
    const float* z1 = (const float*)d_in[0];
    const float* z2 = (const float*)d_in[1];
    float* out = (float*)d_out;

    char* ws = (char*)d_ws;
    unsigned char* zT16 = (unsigned char*)ws;                         // 2 MiB
    float* rowsum   = (float*)(ws + (size_t)2 * 1024 * 1024);         // 32 KiB
    float* pairpart = (float*)(ws + (size_t)2 * 1024 * 1024 + 32768); // 2 KiB
    unsigned int* counter =
        (unsigned int*)(ws + (size_t)2 * 1024 * 1024 + 36864);        // 4 B

    prep_kernel<<<NPAIR / 8, 256, 0, stream>>>(
        z1, z2, zT16, pairpart, rowsum, counter);
    simsum_kernel<<<NTILE, 256, 0, stream>>>(
        zT16, rowsum, pairpart, counter, out);
}

// Round 10
// 91.406 us; speedup vs baseline: 3.5056x; 1.1880x over previous
//
#include <hip/hip_runtime.h>
#include <hip/hip_bf16.h>
#include <math.h>

// NT-Xent loss, N=4096, D=256 -> 2N=8192 rows.
// R21 = R20 resubmit (round-9 failure was "container failed twice" infra,
// same signature as round 1; slot scheme re-audited: unique-writer coverage,
// LDS hazards, bounds all check out).
// R20: R19's counters: simsum 49us, MfmaUtil 12.6%, 19MB traffic -> ~35us
// excess = 1.06M device-scope float RMWs into 32KB (same-line serialization
// at the coherence point). RMW is the expensive primitive; R14's plain
// unique-writer stores + kernel-boundary flush were cheap.
// Fix: deterministic 64-slot unique-writer scheme, NO atomics in simsum:
//   partial[s][row] (2MB): s>panel(row): row-part of block (panel,s);
//   s<panel: col-part of block (s,panel); s==panel: diag block. Every cell
//   written exactly once (poison-proof, no zeroing). LDS pairing folds wave
//   pairs so epilogue = 4 coalesced 64-lane stores per block (~2MB total).
//   K1 prep: normalize -> fp8 -> zT16 + pair sims; zero counter.
//   K2 simsum: LDS-staged fp8 Gram (verified, 0 bank conflicts) + slot store.
//   K3 logsum_final: 128 blocks reduce 64 slots -> log-sums; last-block
//      ticket (R15-validated release/acq_rel) folds pairpart -> out.
// 3 dispatches.

static constexpr int ROWS  = 8192;
static constexpr int NPAIR = 4096;
static constexpr int DIM   = 256;            // f32 elems per row / bytes per fp8 row
static constexpr int NTILE = 64 * 65 / 2;    // 2080
static constexpr float EXP_SCALE = 14.426950408889634f;  // 10/ln2

typedef float f32x4 __attribute__((ext_vector_type(4)));
typedef long  l2v  __attribute__((ext_vector_type(2)));

template <int CTRL>
__device__ __forceinline__ float dpp_add(float x) {
    int t = __builtin_amdgcn_update_dpp(
        0, __builtin_bit_cast(int, x), CTRL, 0xF, 0xF, true);
    return x + __builtin_bit_cast(float, t);
}
__device__ __forceinline__ float sum16(float x) {
    x = dpp_add<0xB1>(x);   // xor 1
    x = dpp_add<0x4E>(x);   // xor 2
    x = dpp_add<0x141>(x);  // xor 4 (row_half_mirror)
    x = dpp_add<0x140>(x);  // xor 8 (row_mirror)
    return x;
}
__device__ __forceinline__ float sum64(float x) {
    x = sum16(x);
    x += __shfl_xor(x, 16);
    x += __shfl_xor(x, 32);
    return x;
}

// ---------------- K1: normalize -> fp8 -> zT16, + pair sims ----------------
// Block b handles pairs p0..p0+7 (p0 = 8b): z1 rows (slots 0..7), z2 rows
// (slots 8..15). Wave w owns slots {w,4+w,8+w,12+w}; it0/it2 = pair p0+w,
// it1/it3 = pair p0+4+w.
// zT16[(c2*8192+row)*16] : c2 = quad*4+kk, entry = 16B =
//   z[row][64kk+8q..+7] ++ z[row][64kk+32+8q..+7]
__global__ void __launch_bounds__(256) prep_kernel(
        const float* __restrict__ z1, const float* __restrict__ z2,
        unsigned char* __restrict__ zT16, float* __restrict__ pairpart,
        unsigned int* __restrict__ counter) {
    __shared__ int Ls[16 * 64];   // 16 rows x 256B (fp8)
    __shared__ float wp[4];
    const int tid  = threadIdx.x;
    const int wave = tid >> 6;
    const int lane = tid & 63;
    const int p0   = blockIdx.x * 8;

    if (blockIdx.x == 0 && tid == 0) counter[0] = 0u;   // d_ws is poisoned

    float4 v[4];
    float  invn[4];
    #pragma unroll
    for (int it = 0; it < 4; ++it) {
        const int s  = it * 4 + wave;          // slot 0..15
        const int pr = p0 + (s & 7);           // pair index
        const float* src = (s < 8) ? (z1 + (size_t)pr * DIM)
                                   : (z2 + (size_t)pr * DIM);
        v[it] = ((const float4*)src)[lane];
        float ss = sum64(v[it].x * v[it].x + v[it].y * v[it].y
                       + v[it].z * v[it].z + v[it].w * v[it].w);
        invn[it] = 1.0f / fmaxf(sqrtf(ss), 1e-12f);
        int p = __builtin_amdgcn_cvt_pk_fp8_f32(
                    v[it].x * invn[it], v[it].y * invn[it], 0, false);
        p     = __builtin_amdgcn_cvt_pk_fp8_f32(
                    v[it].z * invn[it], v[it].w * invn[it], p, true);
        Ls[s * 64 + lane] = p;
    }
    // pair sims: (it0,it2) = pair p0+wave, (it1,it3) = pair p0+4+wave
    {
        float d0 = sum64(v[0].x * v[2].x + v[0].y * v[2].y
                       + v[0].z * v[2].z + v[0].w * v[2].w);
        float d1 = sum64(v[1].x * v[3].x + v[1].y * v[3].y
                       + v[1].z * v[3].z + v[1].w * v[3].w);
        if (lane == 0)
            wp[wave] = (d0 * invn[0] * invn[2] + d1 * invn[1] * invn[3]) * 10.0f;
    }
    __syncthreads();
    // thread t -> c2 = t>>4, row-slot r = t&15
    const int c2 = tid >> 4;
    const int r  = tid & 15;
    const int grow = (r < 8) ? (p0 + r) : (NPAIR + p0 + (r - 8));
    const int quad = c2 >> 2;
    const int kk   = c2 & 3;
    const int d0i = 16 * kk + 2 * quad;
    int4 o;
    o.x = Ls[r * 64 + d0i];
    o.y = Ls[r * 64 + d0i + 1];
    o.z = Ls[r * 64 + d0i + 8];
    o.w = Ls[r * 64 + d0i + 9];
    *(int4*)(zT16 + ((size_t)c2 * ROWS + grow) * 16) = o;
    if (tid == 0)
        pairpart[blockIdx.x] = wp[0] + wp[1] + wp[2] + wp[3];
}

// ---------------- K2: symmetric fp8 Gram, slot-store epilogue ----------
// LDS: A panel [0,32KB), B panel [32KB,64KB); 32 groups of 1KB, group g:
// kk=g>>3, ig=g&7. DMA dest = wave-uniform base + lane*16 -> [q][row][16B];
// compute reads whole 1KB groups contiguously -> 0 bank conflicts.
__global__ void __launch_bounds__(256, 2) simsum_kernel(
        const unsigned char* __restrict__ zT16, float* __restrict__ partial) {
    // decode linear tile index -> (by, bx), bx >= by
    const int t = blockIdx.x;
    int by = (int)floorf((129.0f - sqrtf(16641.0f - 8.0f * (float)t)) * 0.5f);
    by = max(0, min(by, 63));
    while (64 * (by + 1) - ((by + 1) * by) / 2 <= t) by++;
    while (64 * by - (by * (by - 1)) / 2 > t) by--;
    const int bx = by + (t - (64 * by - (by * (by - 1)) / 2));
    const int rowBase = by * 128;
    const int colBase = bx * 128;

    const int tid  = threadIdx.x;
    const int wave = tid >> 6;
    const int lane = tid & 63;
    const int lc   = lane & 15;
    const int quad = lane >> 4;
    const int waveRow = (wave >> 1) * 64;
    const int waveCol = (wave & 1) * 64;

    __shared__ __align__(16) unsigned char lds[65536];

    // ---- stage both panels: waves 0,1 -> A rows, waves 2,3 -> B cols ----
    {
        const int halfSel = wave >> 1;                   // 0=A, 1=B
        const int pbase   = halfSel ? colBase : rowBase;
        #pragma unroll
        for (int it = 0; it < 16; ++it) {
            const int g  = ((wave & 1) << 4) | it;       // 0..31
            const int kk = g >> 3;
            const int ig = g & 7;
            const unsigned char* src = zT16
                + ((size_t)(4 * quad + kk) * ROWS + pbase + 16 * ig + lc) * 16;
            __builtin_amdgcn_global_load_lds(
                (const __attribute__((address_space(1))) unsigned int*)src,
                (__attribute__((address_space(3))) unsigned int*)
                    &lds[(halfSel << 15) + kk * 8192 + ig * 1024],
                16, 0, 0);
        }
    }
    __syncthreads();

    // ---- compute: pure ds_read_b128 + MFMA ----
    const int aig = (wave >> 1) * 4;
    const int bgi = (wave & 1) * 4;
    const unsigned char* lA = &lds[quad * 256 + lc * 16];
    const unsigned char* lB = &lds[32768 + quad * 256 + lc * 16];

    f32x4 acc[4][4];
    #pragma unroll
    for (int i = 0; i < 4; i++)
        #pragma unroll
        for (int j = 0; j < 4; j++)
            acc[i][j] = (f32x4)(0.0f);

    #pragma unroll
    for (int kk = 0; kk < 4; kk++) {
        l2v va[4], vb[4];
        #pragma unroll
        for (int i = 0; i < 4; i++)
            va[i] = *(const l2v*)(lA + kk * 8192 + (aig + i) * 1024);
        #pragma unroll
        for (int j = 0; j < 4; j++)
            vb[j] = *(const l2v*)(lB + kk * 8192 + (bgi + j) * 1024);
        #pragma unroll
        for (int i = 0; i < 4; i++)
            #pragma unroll
            for (int j = 0; j < 4; j++)
                acc[i][j] = __builtin_amdgcn_mfma_f32_16x16x32_fp8_fp8(
                    va[i].x, vb[j].x, acc[i][j], 0, 0, 0);
        #pragma unroll
        for (int i = 0; i < 4; i++)
            #pragma unroll
            for (int j = 0; j < 4; j++)
                acc[i][j] = __builtin_amdgcn_mfma_f32_16x16x32_fp8_fp8(
                    va[i].y, vb[j].y, acc[i][j], 0, 0, 0);
    }

    // ---- epilogue: per-wave sums -> LDS pairing -> 4 coalesced stores ----
    // C/D 16x16: col=lane&15, row=quad*4+reg [m89].
    __syncthreads();                       // all waves done reading panels
    float* rowbuf = (float*)lds;           // [4][64]
    float* colbuf = (float*)(lds + 1024);  // [4][64]

    if (bx == by) {
        #pragma unroll
        for (int i = 0; i < 4; i++) {
            #pragma unroll
            for (int r = 0; r < 4; r++) {
                const int lr   = 16 * i + quad * 4 + r;      // 0..63
                const int grow = rowBase + waveRow + lr;
                float s = 0.0f;
                #pragma unroll
                for (int j = 0; j < 4; j++) {
                    const int gcol = colBase + waveCol + 16 * j + lc;
                    float e = __builtin_amdgcn_exp2f(acc[i][j][r] * EXP_SCALE);
                    s += (grow == gcol) ? 0.0f : e;
                }
                s = sum16(s);
                if (lc == 0) rowbuf[wave * 64 + lr] = s;
            }
        }
    } else {
        float colacc[4] = {0.0f, 0.0f, 0.0f, 0.0f};
        #pragma unroll
        for (int i = 0; i < 4; i++) {
            #pragma unroll
            for (int r = 0; r < 4; r++) {
                const int lr = 16 * i + quad * 4 + r;        // 0..63
                float s = 0.0f;
                #pragma unroll
                for (int j = 0; j < 4; j++) {
                    float e = __builtin_amdgcn_exp2f(acc[i][j][r] * EXP_SCALE);
                    s += e;
                    colacc[j] += e;
                }
                s = sum16(s);
                if (lc == 0) rowbuf[wave * 64 + lr] = s;
            }
        }
        #pragma unroll
        for (int j = 0; j < 4; j++) {
            float c = colacc[j];
            c += __shfl_xor(c, 16);
            c += __shfl_xor(c, 32);
            if (lane < 16) colbuf[wave * 64 + 16 * j + lc] = c;
        }
    }
    __syncthreads();

    // Unique-writer slot stores: partial[s][row], s in 0..63.
    //   rows of panel by -> slot bx (waves 0,1 pair -> rows 0..63;
    //                               waves 2,3 pair -> rows 64..127)
    //   cols of panel bx -> slot by (waveCol 0 pair (w0,w2) -> cols 0..63;
    //                               waveCol 1 pair (w1,w3) -> cols 64..127)
    if (wave == 0)
        partial[(size_t)bx * ROWS + rowBase + lane] =
            rowbuf[0 * 64 + lane] + rowbuf[1 * 64 + lane];
    else if (wave == 2)
        partial[(size_t)bx * ROWS + rowBase + 64 + lane] =
            rowbuf[2 * 64 + lane] + rowbuf[3 * 64 + lane];
    else if (bx != by) {
        if (wave == 1)
            partial[(size_t)by * ROWS + colBase + lane] =
                colbuf[0 * 64 + lane] + colbuf[2 * 64 + lane];
        else
            partial[(size_t)by * ROWS + colBase + 64 + lane] =
                colbuf[1 * 64 + lane] + colbuf[3 * 64 + lane];
    }
}

// ---------------- K3: logsum over 64 slots + last-block final ----------
// out = (sum_rows log(rowsum) - 2 * sum pairpart) / 8192
__global__ void __launch_bounds__(256) logsum_final_kernel(
        const float* __restrict__ partial, const float* __restrict__ pairpart,
        float* __restrict__ logpart, unsigned int* __restrict__ counter,
        float* __restrict__ out) {
    const int tid  = threadIdx.x;
    const int wave = tid >> 6;
    const int lane = tid & 63;
    const int r0 = blockIdx.x * 64;
    float s = 0.0f;
    #pragma unroll
    for (int k = 0; k < 16; ++k) {
        const int slot = wave * 16 + k;
        s += partial[(size_t)slot * ROWS + r0 + lane];
    }
    __shared__ float red[4][64];
    __shared__ unsigned int sdone;
    red[wave][lane] = s;
    __syncthreads();
    if (wave == 0) {
        float rs = red[0][lane] + red[1][lane] + red[2][lane] + red[3][lane];
        float lg = sum64(logf(rs));
        if (lane == 0) {
            __hip_atomic_store(&logpart[blockIdx.x], lg, __ATOMIC_RELEASE,
                               __HIP_MEMORY_SCOPE_AGENT);
            sdone = __hip_atomic_fetch_add(counter, 1u, __ATOMIC_ACQ_REL,
                                           __HIP_MEMORY_SCOPE_AGENT);
        }
    }
    __syncthreads();
    if (sdone == 127) {   // unique last block: all 128 logparts visible
        float v = -2.0f * (pairpart[tid] + pairpart[tid + 256]);
        if (tid < 128)
            v += __hip_atomic_load(&logpart[tid], __ATOMIC_ACQUIRE,
                                   __HIP_MEMORY_SCOPE_AGENT);
        v = sum64(v);
        __shared__ float wpart[4];
        if ((tid & 63) == 0) wpart[tid >> 6] = v;
        __syncthreads();
        if (tid == 0)
            out[0] = (wpart[0] + wpart[1] + wpart[2] + wpart[3])
                   * (1.0f / ROWS);
    }
}

extern "C" void kernel_launch(void* const* d_in, const int* in_sizes, int n_in,
                              void* d_out, int out_size, void* d_ws, size_t ws_size,
                              hipStream_t stream) {
    const float* z1 = (const float*)d_in[0];
    const float* z2 = (const float*)d_in[1];
    float* out = (float*)d_out;

    char* ws = (char*)d_ws;
    unsigned char* zT16 = (unsigned char*)ws;                         // 2 MiB
    float* partial  = (float*)(ws + (size_t)2 * 1024 * 1024);         // 2 MiB [64][8192]
    float* pairpart = (float*)(ws + (size_t)4 * 1024 * 1024);         // 2 KiB (512)
    float* logpart  = (float*)(ws + (size_t)4 * 1024 * 1024 + 4096);  // 512 B (128)
    unsigned int* counter =
        (unsigned int*)(ws + (size_t)4 * 1024 * 1024 + 8192);         // 4 B

    prep_kernel<<<NPAIR / 8, 256, 0, stream>>>(
        z1, z2, zT16, pairpart, counter);
    simsum_kernel<<<NTILE, 256, 0, stream>>>(zT16, partial);
    logsum_final_kernel<<<ROWS / 64, 256, 0, stream>>>(
        partial, pairpart, logpart, counter, out);
}

// Round 11
// 89.946 us; speedup vs baseline: 3.5624x; 1.0162x over previous
//
#include <hip/hip_runtime.h>
#include <hip/hip_bf16.h>
#include <math.h>

// NT-Xent loss, N=4096, D=256 -> 2N=8192 rows.
// R22: R21 passed (91.4us, all our dispatches < 42us poison fill). Two
// named residuals fixed, MFMA datapath untouched:
//  (1) K3 fence storm: 128 x (release-store wbl2 + acq_rel wbl2+inv)
//      ~= 8us (R18 calibration: 2080 pairs ~= 135us). Replace with the
//      R19-VALIDATED cheap pattern: coherence-point atomicExch for logpart
//      (deterministic), __syncthreads vmcnt-drain for ordering, plain
//      atomicAdd ticket, single __threadfence in the winner only.
//  (2) simsum L2 locality: 2080 % 8 == 0 -> bijective XCD swizzle
//      t = (b&7)*260 + b/8 gives each XCD 260 consecutive tiles ->
//      32KB panel reuse (65x) hits local L2 instead of cross-XCD L3.
//   K1 prep: normalize -> fp8 -> zT16 + pair sims; zero counter.
//   K2 simsum: LDS-staged fp8 Gram (verified, 0 bank conflicts),
//      64-slot unique-writer store (no atomics, poison-proof).
//   K3 logsum_final: 128 blocks reduce slots -> logpart via atomicExch;
//      last-ticket block folds logpart + pairpart -> out.
// 3 dispatches.

static constexpr int ROWS  = 8192;
static constexpr int NPAIR = 4096;
static constexpr int DIM   = 256;            // f32 elems per row / bytes per fp8 row
static constexpr int NTILE = 64 * 65 / 2;    // 2080 = 8 * 260
static constexpr float EXP_SCALE = 14.426950408889634f;  // 10/ln2

typedef float f32x4 __attribute__((ext_vector_type(4)));
typedef long  l2v  __attribute__((ext_vector_type(2)));

template <int CTRL>
__device__ __forceinline__ float dpp_add(float x) {
    int t = __builtin_amdgcn_update_dpp(
        0, __builtin_bit_cast(int, x), CTRL, 0xF, 0xF, true);
    return x + __builtin_bit_cast(float, t);
}
__device__ __forceinline__ float sum16(float x) {
    x = dpp_add<0xB1>(x);   // xor 1
    x = dpp_add<0x4E>(x);   // xor 2
    x = dpp_add<0x141>(x);  // xor 4 (row_half_mirror)
    x = dpp_add<0x140>(x);  // xor 8 (row_mirror)
    return x;
}
__device__ __forceinline__ float sum64(float x) {
    x = sum16(x);
    x += __shfl_xor(x, 16);
    x += __shfl_xor(x, 32);
    return x;
}

// ---------------- K1: normalize -> fp8 -> zT16, + pair sims ----------------
// Block b handles pairs p0..p0+7 (p0 = 8b): z1 rows (slots 0..7), z2 rows
// (slots 8..15). Wave w owns slots {w,4+w,8+w,12+w}; it0/it2 = pair p0+w,
// it1/it3 = pair p0+4+w.
// zT16[(c2*8192+row)*16] : c2 = quad*4+kk, entry = 16B =
//   z[row][64kk+8q..+7] ++ z[row][64kk+32+8q..+7]
__global__ void __launch_bounds__(256) prep_kernel(
        const float* __restrict__ z1, const float* __restrict__ z2,
        unsigned char* __restrict__ zT16, float* __restrict__ pairpart,
        unsigned int* __restrict__ counter) {
    __shared__ int Ls[16 * 64];   // 16 rows x 256B (fp8)
    __shared__ float wp[4];
    const int tid  = threadIdx.x;
    const int wave = tid >> 6;
    const int lane = tid & 63;
    const int p0   = blockIdx.x * 8;

    if (blockIdx.x == 0 && tid == 0) counter[0] = 0u;   // d_ws is poisoned

    float4 v[4];
    float  invn[4];
    #pragma unroll
    for (int it = 0; it < 4; ++it) {
        const int s  = it * 4 + wave;          // slot 0..15
        const int pr = p0 + (s & 7);           // pair index
        const float* src = (s < 8) ? (z1 + (size_t)pr * DIM)
                                   : (z2 + (size_t)pr * DIM);
        v[it] = ((const float4*)src)[lane];
        float ss = sum64(v[it].x * v[it].x + v[it].y * v[it].y
                       + v[it].z * v[it].z + v[it].w * v[it].w);
        invn[it] = 1.0f / fmaxf(sqrtf(ss), 1e-12f);
        int p = __builtin_amdgcn_cvt_pk_fp8_f32(
                    v[it].x * invn[it], v[it].y * invn[it], 0, false);
        p     = __builtin_amdgcn_cvt_pk_fp8_f32(
                    v[it].z * invn[it], v[it].w * invn[it], p, true);
        Ls[s * 64 + lane] = p;
    }
    // pair sims: (it0,it2) = pair p0+wave, (it1,it3) = pair p0+4+wave
    {
        float d0 = sum64(v[0].x * v[2].x + v[0].y * v[2].y
                       + v[0].z * v[2].z + v[0].w * v[2].w);
        float d1 = sum64(v[1].x * v[3].x + v[1].y * v[3].y
                       + v[1].z * v[3].z + v[1].w * v[3].w);
        if (lane == 0)
            wp[wave] = (d0 * invn[0] * invn[2] + d1 * invn[1] * invn[3]) * 10.0f;
    }
    __syncthreads();
    // thread t -> c2 = t>>4, row-slot r = t&15
    const int c2 = tid >> 4;
    const int r  = tid & 15;
    const int grow = (r < 8) ? (p0 + r) : (NPAIR + p0 + (r - 8));
    const int quad = c2 >> 2;
    const int kk   = c2 & 3;
    const int d0i = 16 * kk + 2 * quad;
    int4 o;
    o.x = Ls[r * 64 + d0i];
    o.y = Ls[r * 64 + d0i + 1];
    o.z = Ls[r * 64 + d0i + 8];
    o.w = Ls[r * 64 + d0i + 9];
    *(int4*)(zT16 + ((size_t)c2 * ROWS + grow) * 16) = o;
    if (tid == 0)
        pairpart[blockIdx.x] = wp[0] + wp[1] + wp[2] + wp[3];
}

// ---------------- K2: symmetric fp8 Gram, slot-store epilogue ----------
// LDS: A panel [0,32KB), B panel [32KB,64KB); 32 groups of 1KB, group g:
// kk=g>>3, ig=g&7. DMA dest = wave-uniform base + lane*16 -> [q][row][16B];
// compute reads whole 1KB groups contiguously -> 0 bank conflicts.
__global__ void __launch_bounds__(256, 2) simsum_kernel(
        const unsigned char* __restrict__ zT16, float* __restrict__ partial) {
    // XCD-aware bijective swizzle (NTILE = 2080 = 8*260): each XCD gets 260
    // consecutive tiles -> panel reuse lands in local L2.
    const int t = (blockIdx.x & 7) * (NTILE / 8) + (blockIdx.x >> 3);
    // decode linear tile index -> (by, bx), bx >= by
    int by = (int)floorf((129.0f - sqrtf(16641.0f - 8.0f * (float)t)) * 0.5f);
    by = max(0, min(by, 63));
    while (64 * (by + 1) - ((by + 1) * by) / 2 <= t) by++;
    while (64 * by - (by * (by - 1)) / 2 > t) by--;
    const int bx = by + (t - (64 * by - (by * (by - 1)) / 2));
    const int rowBase = by * 128;
    const int colBase = bx * 128;

    const int tid  = threadIdx.x;
    const int wave = tid >> 6;
    const int lane = tid & 63;
    const int lc   = lane & 15;
    const int quad = lane >> 4;
    const int waveRow = (wave >> 1) * 64;
    const int waveCol = (wave & 1) * 64;

    __shared__ __align__(16) unsigned char lds[65536];

    // ---- stage both panels: waves 0,1 -> A rows, waves 2,3 -> B cols ----
    {
        const int halfSel = wave >> 1;                   // 0=A, 1=B
        const int pbase   = halfSel ? colBase : rowBase;
        #pragma unroll
        for (int it = 0; it < 16; ++it) {
            const int g  = ((wave & 1) << 4) | it;       // 0..31
            const int kk = g >> 3;
            const int ig = g & 7;
            const unsigned char* src = zT16
                + ((size_t)(4 * quad + kk) * ROWS + pbase + 16 * ig + lc) * 16;
            __builtin_amdgcn_global_load_lds(
                (const __attribute__((address_space(1))) unsigned int*)src,
                (__attribute__((address_space(3))) unsigned int*)
                    &lds[(halfSel << 15) + kk * 8192 + ig * 1024],
                16, 0, 0);
        }
    }
    __syncthreads();

    // ---- compute: pure ds_read_b128 + MFMA ----
    const int aig = (wave >> 1) * 4;
    const int bgi = (wave & 1) * 4;
    const unsigned char* lA = &lds[quad * 256 + lc * 16];
    const unsigned char* lB = &lds[32768 + quad * 256 + lc * 16];

    f32x4 acc[4][4];
    #pragma unroll
    for (int i = 0; i < 4; i++)
        #pragma unroll
        for (int j = 0; j < 4; j++)
            acc[i][j] = (f32x4)(0.0f);

    #pragma unroll
    for (int kk = 0; kk < 4; kk++) {
        l2v va[4], vb[4];
        #pragma unroll
        for (int i = 0; i < 4; i++)
            va[i] = *(const l2v*)(lA + kk * 8192 + (aig + i) * 1024);
        #pragma unroll
        for (int j = 0; j < 4; j++)
            vb[j] = *(const l2v*)(lB + kk * 8192 + (bgi + j) * 1024);
        #pragma unroll
        for (int i = 0; i < 4; i++)
            #pragma unroll
            for (int j = 0; j < 4; j++)
                acc[i][j] = __builtin_amdgcn_mfma_f32_16x16x32_fp8_fp8(
                    va[i].x, vb[j].x, acc[i][j], 0, 0, 0);
        #pragma unroll
        for (int i = 0; i < 4; i++)
            #pragma unroll
            for (int j = 0; j < 4; j++)
                acc[i][j] = __builtin_amdgcn_mfma_f32_16x16x32_fp8_fp8(
                    va[i].y, vb[j].y, acc[i][j], 0, 0, 0);
    }

    // ---- epilogue: per-wave sums -> LDS pairing -> 4 coalesced stores ----
    // C/D 16x16: col=lane&15, row=quad*4+reg [m89].
    __syncthreads();                       // all waves done reading panels
    float* rowbuf = (float*)lds;           // [4][64]
    float* colbuf = (float*)(lds + 1024);  // [4][64]

    if (bx == by) {
        #pragma unroll
        for (int i = 0; i < 4; i++) {
            #pragma unroll
            for (int r = 0; r < 4; r++) {
                const int lr   = 16 * i + quad * 4 + r;      // 0..63
                const int grow = rowBase + waveRow + lr;
                float s = 0.0f;
                #pragma unroll
                for (int j = 0; j < 4; j++) {
                    const int gcol = colBase + waveCol + 16 * j + lc;
                    float e = __builtin_amdgcn_exp2f(acc[i][j][r] * EXP_SCALE);
                    s += (grow == gcol) ? 0.0f : e;
                }
                s = sum16(s);
                if (lc == 0) rowbuf[wave * 64 + lr] = s;
            }
        }
    } else {
        float colacc[4] = {0.0f, 0.0f, 0.0f, 0.0f};
        #pragma unroll
        for (int i = 0; i < 4; i++) {
            #pragma unroll
            for (int r = 0; r < 4; r++) {
                const int lr = 16 * i + quad * 4 + r;        // 0..63
                float s = 0.0f;
                #pragma unroll
                for (int j = 0; j < 4; j++) {
                    float e = __builtin_amdgcn_exp2f(acc[i][j][r] * EXP_SCALE);
                    s += e;
                    colacc[j] += e;
                }
                s = sum16(s);
                if (lc == 0) rowbuf[wave * 64 + lr] = s;
            }
        }
        #pragma unroll
        for (int j = 0; j < 4; j++) {
            float c = colacc[j];
            c += __shfl_xor(c, 16);
            c += __shfl_xor(c, 32);
            if (lane < 16) colbuf[wave * 64 + 16 * j + lc] = c;
        }
    }
    __syncthreads();

    // Unique-writer slot stores: partial[s][row], s in 0..63.
    //   rows of panel by -> slot bx (waves 0,1 pair -> rows 0..63;
    //                               waves 2,3 pair -> rows 64..127)
    //   cols of panel bx -> slot by (waveCol 0 pair (w0,w2) -> cols 0..63;
    //                               waveCol 1 pair (w1,w3) -> cols 64..127)
    if (wave == 0)
        partial[(size_t)bx * ROWS + rowBase + lane] =
            rowbuf[0 * 64 + lane] + rowbuf[1 * 64 + lane];
    else if (wave == 2)
        partial[(size_t)bx * ROWS + rowBase + 64 + lane] =
            rowbuf[2 * 64 + lane] + rowbuf[3 * 64 + lane];
    else if (bx != by) {
        if (wave == 1)
            partial[(size_t)by * ROWS + colBase + lane] =
                colbuf[0 * 64 + lane] + colbuf[2 * 64 + lane];
        else
            partial[(size_t)by * ROWS + colBase + 64 + lane] =
                colbuf[1 * 64 + lane] + colbuf[3 * 64 + lane];
    }
}

// ---------------- K3: logsum over 64 slots + last-ticket final ----------
// out = (sum_rows log(rowsum) - 2 * sum pairpart) / 8192
// R19-validated sync: coherence-point RMW (atomicExch) for logpart,
// __syncthreads vmcnt-drain orders it before the plain ticket; single
// __threadfence in the winner refetches from the coherence point.
__global__ void __launch_bounds__(256) logsum_final_kernel(
        const float* __restrict__ partial, const float* __restrict__ pairpart,
        float* __restrict__ logpart, unsigned int* __restrict__ counter,
        float* __restrict__ out) {
    const int tid  = threadIdx.x;
    const int wave = tid >> 6;
    const int lane = tid & 63;
    const int r0 = blockIdx.x * 64;
    float s = 0.0f;
    #pragma unroll
    for (int k = 0; k < 16; ++k) {
        const int slot = wave * 16 + k;
        s += partial[(size_t)slot * ROWS + r0 + lane];
    }
    __shared__ float red[4][64];
    __shared__ unsigned int sdone;
    red[wave][lane] = s;
    __syncthreads();
    if (wave == 0) {
        float rs = red[0][lane] + red[1][lane] + red[2][lane] + red[3][lane];
        float lg = sum64(logf(rs));
        if (lane == 0) atomicExch(&logpart[blockIdx.x], lg);  // CP store, no fence
    }
    __syncthreads();              // vmcnt(0) drain: exch performed
    if (tid == 0)
        sdone = atomicAdd(counter, 1u);   // plain ticket, no cache ops
    __syncthreads();
    if (sdone == 127) {           // unique winner: all 128 logparts at CP
        __threadfence();          // ONE block: invalidate local caches
        float v = -2.0f * (pairpart[tid] + pairpart[tid + 256]);
        if (tid < 128) v += logpart[tid];
        v = sum64(v);
        __shared__ float wpart[4];
        if ((tid & 63) == 0) wpart[tid >> 6] = v;
        __syncthreads();
        if (tid == 0)
            out[0] = (wpart[0] + wpart[1] + wpart[2] + wpart[3])
                   * (1.0f / ROWS);
    }
}

extern "C" void kernel_launch(void* const* d_in, const int* in_sizes, int n_in,
                              void* d_out, int out_size, void* d_ws, size_t ws_size,
                              hipStream_t stream) {
    const float* z1 = (const float*)d_in[0];
    const float* z2 = (const float*)d_in[1];
    float* out = (float*)d_out;

    char* ws = (char*)d_ws;
    unsigned char* zT16 = (unsigned char*)ws;                         // 2 MiB
    float* partial  = (float*)(ws + (size_t)2 * 1024 * 1024);         // 2 MiB [64][8192]
    float* pairpart = (float*)(ws + (size_t)4 * 1024 * 1024);         // 2 KiB (512)
    float* logpart  = (float*)(ws + (size_t)4 * 1024 * 1024 + 4096);  // 512 B (128)
    unsigned int* counter =
        (unsigned int*)(ws + (size_t)4 * 1024 * 1024 + 8192);         // 4 B

    prep_kernel<<<NPAIR / 8, 256, 0, stream>>>(
        z1, z2, zT16, pairpart, counter);
    simsum_kernel<<<NTILE, 256, 0, stream>>>(zT16, partial);
    logsum_final_kernel<<<ROWS / 64, 256, 0, stream>>>(
        partial, pairpart, logpart, counter, out);
}